// Round 2
// baseline (434.961 us; speedup 1.0000x reference)
//
#include <hip/hip_runtime.h>

// Q = L L^T for packed lower-triangular 3x3 Cholesky factors.
// packed order: a=(0,0) b=(1,0) c=(1,1) d=(2,0) e=(2,1) f=(2,2)
//
// LDS-staged, fully coalesced. vs 422.9us baseline:
//   B 1024 -> 512: LDS 36 KB -> 18 KB, 4 -> 8 blocks/CU (16 -> 32 waves/CU,
//   100% occupancy) to cover the 3 barrier drains per block.
//   Output stores are nontemporal (write-once data, keep L2/L3 clean).
//   Uses clang ext_vector_type for the nontemporal builtin (HIP float4 is
//   a struct and the builtin rejects it).

typedef float floatx4 __attribute__((ext_vector_type(4)));

constexpr int B = 512;  // batches per block (8388608 % 512 == 0)
constexpr int T = 256;  // threads per block (4 waves)

__global__ __launch_bounds__(T, 8) void getcov_kernel(
    const float* __restrict__ in, float* __restrict__ out) {
  __shared__ floatx4 lds4[(9 * B) / 4];  // 18 KB; input phase uses first 12 KB
  float* lds = reinterpret_cast<float*>(lds4);
  const float2* lds2 = reinterpret_cast<const float2*>(lds4);

  const int tid = threadIdx.x;
  const size_t base_b = (size_t)blockIdx.x * B;

  // ---- stage: global -> LDS, fully coalesced 16B loads (3 per thread) ----
  const floatx4* __restrict__ gin =
      reinterpret_cast<const floatx4*>(in) + (base_b * 6) / 4;
#pragma unroll
  for (int j = 0; j < 3; ++j) {
    lds4[tid + T * j] = gin[tid + T * j];
  }
  __syncthreads();

  // ---- compute: 2 batches/thread, results held in registers ----
  // float2 reads, lane stride 24 B -> 2-way bank aliasing (free on wave64)
  float q[2][6];
#pragma unroll
  for (int j = 0; j < 2; ++j) {
    const int b = tid + T * j;
    const float2 p0 = lds2[3 * b + 0];
    const float2 p1 = lds2[3 * b + 1];
    const float2 p2 = lds2[3 * b + 2];
    const float a = p0.x, bb = p0.y, c = p1.x, d = p1.y, e = p2.x, f = p2.y;
    q[j][0] = a * a;                  // Q00
    q[j][1] = a * bb;                 // Q01 = Q10
    q[j][2] = a * d;                  // Q02 = Q20
    q[j][3] = bb * bb + c * c;        // Q11
    q[j][4] = bb * d + c * e;         // Q12 = Q21
    q[j][5] = d * d + e * e + f * f;  // Q22
  }
  __syncthreads();  // all LDS reads done before overwriting buffer

  // ---- scatter results into LDS in output order ----
  // lane stride 9 words, gcd(9,32)=1 -> conflict-free
#pragma unroll
  for (int j = 0; j < 2; ++j) {
    const int b = tid + T * j;
    float* o = &lds[9 * b];
    o[0] = q[j][0]; o[1] = q[j][1]; o[2] = q[j][2];
    o[3] = q[j][1]; o[4] = q[j][3]; o[5] = q[j][4];
    o[6] = q[j][2]; o[7] = q[j][4]; o[8] = q[j][5];
  }
  __syncthreads();

  // ---- store: LDS -> global, coalesced nontemporal 16B stores ----
  // 9*B/4 = 1152 = 4.5*T; waves 0,1 do 5 iters, waves 2,3 do 4 (wave-uniform)
  floatx4* __restrict__ gout =
      reinterpret_cast<floatx4*>(out) + (base_b * 9) / 4;
  for (int idx = tid; idx < (9 * B) / 4; idx += T) {
    __builtin_nontemporal_store(lds4[idx], gout + idx);
  }
}

extern "C" void kernel_launch(void* const* d_in, const int* in_sizes, int n_in,
                              void* d_out, int out_size, void* d_ws, size_t ws_size,
                              hipStream_t stream) {
  const float* in = (const float*)d_in[0];
  float* out = (float*)d_out;
  const int nbatch = in_sizes[0] / 6;  // 8388608
  const int grid = nbatch / B;         // exact: 16384 blocks
  getcov_kernel<<<grid, T, 0, stream>>>(in, out);
}

// Round 3
// 405.642 us; speedup vs baseline: 1.0723x; 1.0723x over previous
//
#include <hip/hip_runtime.h>

// Q = L L^T for packed lower-triangular 3x3 Cholesky factors.
// packed order: a=(0,0) b=(1,0) c=(1,1) d=(2,0) e=(2,1) f=(2,2)
//
// LDS-staged version for perfect global coalescing:
//   stage in (24 KB, float4, lane-contiguous) -> compute in regs ->
//   scatter to LDS in output order (stride 9, conflict-free) ->
//   store out (36 KB, float4, lane-contiguous).
// 36 KB LDS -> 4 blocks/CU (16 waves/CU).
//
// Session notes:
//   - B=512 + nontemporal stores: 435.0 us (REGRESSION). nt forces the
//     302 MB output to drain fully to HBM before kernel completion instead
//     of completing at the L2/L3 coherence point. Normal stores win.
//   - dur_us includes 2x ~186us harness poison fills (fixed cost, 373 us);
//     this kernel's own share is ~51 us vs a ~48 us HBM write-drain floor.

constexpr int B = 1024;  // batches per block (8388608 % 1024 == 0)
constexpr int T = 256;   // threads per block

__global__ __launch_bounds__(T) void getcov_kernel(
    const float* __restrict__ in, float* __restrict__ out) {
  __shared__ float4 lds4[(9 * B) / 4];  // 36 KB; input phase uses first 24 KB
  float* lds = reinterpret_cast<float*>(lds4);

  const int tid = threadIdx.x;
  const size_t base_b = (size_t)blockIdx.x * B;

  // ---- stage: global -> LDS, fully coalesced float4 ----
  const float4* __restrict__ gin =
      reinterpret_cast<const float4*>(in) + (base_b * 6) / 4;
#pragma unroll
  for (int j = 0; j < 6; ++j) {
    lds4[tid + T * j] = gin[tid + T * j];
  }
  __syncthreads();

  // ---- compute: 4 batches/thread, results held in registers ----
  // lane stride 6 words -> 2-way bank aliasing (free on wave64/32-bank)
  float q[4][6];
#pragma unroll
  for (int j = 0; j < 4; ++j) {
    const int b = tid + T * j;
    const float* p = &lds[6 * b];
    const float a = p[0], bb = p[1], c = p[2], d = p[3], e = p[4], f = p[5];
    q[j][0] = a * a;                       // Q00
    q[j][1] = a * bb;                      // Q01 = Q10
    q[j][2] = a * d;                       // Q02 = Q20
    q[j][3] = bb * bb + c * c;             // Q11
    q[j][4] = bb * d + c * e;              // Q12 = Q21
    q[j][5] = d * d + e * e + f * f;       // Q22
  }
  __syncthreads();  // all LDS reads done before overwriting buffer

  // ---- scatter results into LDS in output order ----
  // lane stride 9 words, gcd(9,32)=1 -> conflict-free
#pragma unroll
  for (int j = 0; j < 4; ++j) {
    const int b = tid + T * j;
    float* o = &lds[9 * b];
    o[0] = q[j][0]; o[1] = q[j][1]; o[2] = q[j][2];
    o[3] = q[j][1]; o[4] = q[j][3]; o[5] = q[j][4];
    o[6] = q[j][2]; o[7] = q[j][4]; o[8] = q[j][5];
  }
  __syncthreads();

  // ---- store: LDS -> global, fully coalesced float4 ----
  float4* __restrict__ gout =
      reinterpret_cast<float4*>(out) + (base_b * 9) / 4;
#pragma unroll
  for (int j = 0; j < 9; ++j) {
    gout[tid + T * j] = lds4[tid + T * j];
  }
}

extern "C" void kernel_launch(void* const* d_in, const int* in_sizes, int n_in,
                              void* d_out, int out_size, void* d_ws, size_t ws_size,
                              hipStream_t stream) {
  const float* in = (const float*)d_in[0];
  float* out = (float*)d_out;
  const int nbatch = in_sizes[0] / 6;  // 8388608
  const int grid = nbatch / B;         // exact: 8192 blocks
  getcov_kernel<<<grid, T, 0, stream>>>(in, out);
}